// Round 1
// baseline (584.031 us; speedup 1.0000x reference)
//
#include <hip/hip_runtime.h>
#include <math.h>

#define NROWS 48000
#define KDIM 512
#define NE 320
#define GE 640
#define DDIM 384
#define ODIM 768
#define CB_OFF 36864000ul
#define SC_OFF 67584000ul
#define MARGIN 2e-3f

#define BM 64
#define BN 64
#define BK 32

// ---------------- Kernel A: logits = X @ W^T + b (fp32, vector FMA) -------
__global__ __launch_bounds__(256) void gemm_logits(
    const float* __restrict__ X,     // [48000,512]
    const float* __restrict__ W,     // [640,512]
    const float* __restrict__ bvec,  // [640]
    float* __restrict__ Lout)        // [48000,640]  (aliases cb region of d_out)
{
    __shared__ float As[BK][BM + 4];
    __shared__ float Bs[BK][BN + 4];
    const int bm = blockIdx.x;   // 750
    const int bn = blockIdx.y;   // 10
    const int tid = threadIdx.x;
    const int tx = tid & 15;     // 16 cols of threads
    const int ty = tid >> 4;     // 16 rows of threads

    const float* Ablk = X + (size_t)bm * BM * KDIM;
    const float* Bblk = W + (size_t)bn * BN * KDIM;

    float acc[4][4];
    #pragma unroll
    for (int i = 0; i < 4; ++i)
        #pragma unroll
        for (int j = 0; j < 4; ++j) acc[i][j] = 0.f;

    for (int kk = 0; kk < KDIM; kk += BK) {
        // stage 64x32 A and B tiles (512 float4 each, 2 per thread), transposed in LDS
        #pragma unroll
        for (int t = 0; t < 2; ++t) {
            int f4 = tid + t * 256;
            int row = f4 >> 3;
            int kq = f4 & 7;
            float4 va = *reinterpret_cast<const float4*>(Ablk + (size_t)row * KDIM + kk + kq * 4);
            As[kq * 4 + 0][row] = va.x; As[kq * 4 + 1][row] = va.y;
            As[kq * 4 + 2][row] = va.z; As[kq * 4 + 3][row] = va.w;
            float4 vb = *reinterpret_cast<const float4*>(Bblk + (size_t)row * KDIM + kk + kq * 4);
            Bs[kq * 4 + 0][row] = vb.x; Bs[kq * 4 + 1][row] = vb.y;
            Bs[kq * 4 + 2][row] = vb.z; Bs[kq * 4 + 3][row] = vb.w;
        }
        __syncthreads();
        #pragma unroll
        for (int k = 0; k < BK; ++k) {
            float4 a = *reinterpret_cast<const float4*>(&As[k][ty * 4]);
            float4 bq = *reinterpret_cast<const float4*>(&Bs[k][tx * 4]);
            float av[4] = {a.x, a.y, a.z, a.w};
            float bv[4] = {bq.x, bq.y, bq.z, bq.w};
            #pragma unroll
            for (int i = 0; i < 4; ++i)
                #pragma unroll
                for (int j = 0; j < 4; ++j)
                    acc[i][j] = fmaf(av[i], bv[j], acc[i][j]);
        }
        __syncthreads();
    }

    const int m0 = bm * BM + ty * 4;
    const int n0 = bn * BN + tx * 4;
    float4 bb = *reinterpret_cast<const float4*>(bvec + n0);
    #pragma unroll
    for (int i = 0; i < 4; ++i) {
        float4 o;
        o.x = acc[i][0] + bb.x;
        o.y = acc[i][1] + bb.y;
        o.z = acc[i][2] + bb.z;
        o.w = acc[i][3] + bb.w;
        *reinterpret_cast<float4*>(Lout + (size_t)(m0 + i) * GE + n0) = o;
    }
}

// ---------------- Kernel B: per-row epilogue ------------------------------
__device__ __forceinline__ bool better(float a, int ia, float b, int ib) {
    return (a > b) || (a == b && ia < ib);
}

// top-2 (value,index) across a 32-lane half; v[i] corresponds to e = il + 32*i
__device__ __forceinline__ void top2_half(const float* v, int il,
                                          float& v1, int& i1, float& v2, int& i2)
{
    v1 = -3.4e38f; i1 = 0x7fffffff;
    v2 = -3.4e38f; i2 = 0x7fffffff;
    #pragma unroll
    for (int i = 0; i < 10; ++i) {
        int e = il + 32 * i;
        float x = v[i];
        if (better(x, e, v1, i1)) { v2 = v1; i2 = i1; v1 = x; i1 = e; }
        else if (better(x, e, v2, i2)) { v2 = x; i2 = e; }
    }
    #pragma unroll
    for (int m = 1; m <= 16; m <<= 1) {
        float ov1 = __shfl_xor(v1, m); int oi1 = __shfl_xor(i1, m);
        float ov2 = __shfl_xor(v2, m); int oi2 = __shfl_xor(i2, m);
        float lv; int li;
        if (better(ov1, oi1, v1, i1)) { lv = v1; li = i1; v1 = ov1; i1 = oi1; }
        else { lv = ov1; li = oi1; }
        if (better(lv, li, v2, i2)) { v2 = lv; i2 = li; }
        if (better(ov2, oi2, v2, i2)) { v2 = ov2; i2 = oi2; }
    }
}

// fp64 re-resolution of a near-tied argmax between candidates c1,c2
__device__ int resolve2(const float* __restrict__ X, const float* __restrict__ W,
                        const float* __restrict__ bvec, const float* __restrict__ Urow,
                        int n, int h, int c1, int c2, bool gum, int il)
{
    const float* xr = X + (size_t)n * KDIM;
    const float* w1 = W + (size_t)(h * NE + c1) * KDIM;
    const float* w2 = W + (size_t)(h * NE + c2) * KDIM;
    double d1 = 0.0, d2 = 0.0;
    #pragma unroll
    for (int j = 0; j < 16; ++j) {
        int k = il + 32 * j;
        double xv = (double)xr[k];
        d1 += xv * (double)w1[k];
        d2 += xv * (double)w2[k];
    }
    #pragma unroll
    for (int m = 1; m <= 16; m <<= 1) {
        d1 += __shfl_xor(d1, m);
        d2 += __shfl_xor(d2, m);
    }
    d1 += (double)bvec[h * NE + c1];
    d2 += (double)bvec[h * NE + c2];
    if (gum) {
        d1 += -log(-log((double)Urow[c1] + 1e-10) + 1e-10);
        d2 += -log(-log((double)Urow[c2] + 1e-10) + 1e-10);
    }
    return (d2 > d1 || (d2 == d1 && c2 < c1)) ? c2 : c1;
}

__global__ __launch_bounds__(256) void epilogue_kernel(
    const float* __restrict__ X, const float* __restrict__ W,
    const float* __restrict__ bvec, const float* __restrict__ entries,
    const float* __restrict__ gumbel, float* __restrict__ out,
    float* __restrict__ gavgp, unsigned int* __restrict__ gcnt)
{
    __shared__ float s_avgp[GE];
    __shared__ unsigned int s_cnt[GE];
    const int tid = threadIdx.x;
    for (int i = tid; i < GE; i += 256) { s_avgp[i] = 0.f; s_cnt[i] = 0u; }
    __syncthreads();

    const int wave = tid >> 6, lane = tid & 63;
    const int h = lane >> 5, il = lane & 31;   // h = codebook, il = lane-in-half

    float accp[10];
    #pragma unroll
    for (int i = 0; i < 10; ++i) accp[i] = 0.f;

    float* cb = out + CB_OFF;

    for (int rr = 0; rr < 8; ++rr) {
        const int n = blockIdx.x * 32 + wave * 8 + rr;
        float* Lrow = cb + (size_t)n * GE + h * NE;            // logits (read) then one-hot (write)
        const float* Urow = gumbel + (size_t)(2 * n + h) * NE;

        float lg[10], zg[10];
        #pragma unroll
        for (int i = 0; i < 10; ++i) {
            int e = il + 32 * i;
            lg[i] = Lrow[e];
            float gn = -logf(-logf(Urow[e] + 1e-10f) + 1e-10f);
            zg[i] = lg[i] + gn;
        }

        float pv1, pv2; int pi1, pi2;
        top2_half(lg, il, pv1, pi1, pv2, pi2);
        float gv1, gv2; int gi1, gi2;
        top2_half(zg, il, gv1, gi1, gv2, gi2);

        int k_plain = pi1;
        if (pv1 - pv2 < MARGIN)
            k_plain = resolve2(X, W, bvec, Urow, n, h, pi1, pi2, false, il);
        int k_g = gi1;
        if (gv1 - gv2 < MARGIN)
            k_g = resolve2(X, W, bvec, Urow, n, h, gi1, gi2, true, il);

        // softmax(logits) accumulated for prob_perplexity
        float s = 0.f, ex[10];
        #pragma unroll
        for (int i = 0; i < 10; ++i) { ex[i] = expf(lg[i] - pv1); s += ex[i]; }
        #pragma unroll
        for (int m = 1; m <= 16; m <<= 1) s += __shfl_xor(s, m);
        float inv = 1.f / s;
        #pragma unroll
        for (int i = 0; i < 10; ++i) accp[i] += ex[i] * inv;

        if (il == 0) atomicAdd(&s_cnt[h * NE + k_plain], 1u);

        // cb one-hot (overwrites the logits row we already consumed)
        #pragma unroll
        for (int i = 0; i < 10; ++i) {
            int e = il + 32 * i;
            Lrow[e] = (e == k_g) ? 1.f : 0.f;
        }
        // quantized = gather of entries[g, k_g, :]
        const float* ent = entries + (size_t)(h * NE + k_g) * DDIM;
        float* qrow = out + (size_t)n * ODIM + h * DDIM;
        #pragma unroll
        for (int j = 0; j < 12; ++j) {
            int d = il + 32 * j;
            qrow[d] = ent[d];
        }
    }

    #pragma unroll
    for (int i = 0; i < 10; ++i)
        atomicAdd(&s_avgp[h * NE + il + 32 * i], accp[i]);
    __syncthreads();
    for (int i = tid; i < GE; i += 256) {
        atomicAdd(&gavgp[i], s_avgp[i]);
        unsigned int c = s_cnt[i];
        if (c) atomicAdd(&gcnt[i], c);
    }
}

// ---------------- Kernel C: perplexity scalars ----------------------------
__global__ void finalize_kernel(const float* __restrict__ gavgp,
                                const unsigned int* __restrict__ gcnt,
                                float* __restrict__ out)
{
    __shared__ double sc[GE], sp[GE];
    const int t = threadIdx.x;
    if (t < GE) {
        double hp = (double)gcnt[t] * (1.0 / 48000.0);
        sc[t] = hp * log(hp + 1e-7);
        double ap = (double)gavgp[t] * (1.0 / 48000.0);
        sp[t] = ap * log(ap + 1e-7);
    }
    __syncthreads();
    if (t == 0) {
        double c0 = 0, c1 = 0, p0 = 0, p1 = 0;
        for (int e = 0; e < NE; ++e) { c0 += sc[e]; p0 += sp[e]; }
        for (int e = NE; e < GE; ++e) { c1 += sc[e]; p1 += sp[e]; }
        out[SC_OFF]     = (float)(exp(-c0) + exp(-c1));
        out[SC_OFF + 1] = (float)(exp(-p0) + exp(-p1));
    }
}

// ---------------- launch --------------------------------------------------
extern "C" void kernel_launch(void* const* d_in, const int* in_sizes, int n_in,
                              void* d_out, int out_size, void* d_ws, size_t ws_size,
                              hipStream_t stream)
{
    const float* X       = (const float*)d_in[0];
    const float* W       = (const float*)d_in[1];
    const float* bvec    = (const float*)d_in[2];
    const float* entries = (const float*)d_in[3];
    const float* gumbel  = (const float*)d_in[4];
    float* out = (float*)d_out;

    float* gavgp = (float*)d_ws;
    unsigned int* gcnt = (unsigned int*)((char*)d_ws + GE * sizeof(float));

    hipMemsetAsync(d_ws, 0, GE * 8, stream);
    gemm_logits<<<dim3(750, 10), 256, 0, stream>>>(X, W, bvec, out + CB_OFF);
    epilogue_kernel<<<1500, 256, 0, stream>>>(X, W, bvec, entries, gumbel, out, gavgp, gcnt);
    finalize_kernel<<<1, 640, 0, stream>>>(gavgp, gcnt, out);
}

// Round 2
// 292.463 us; speedup vs baseline: 1.9969x; 1.9969x over previous
//
#include <hip/hip_runtime.h>
#include <math.h>
#include <stdint.h>

#define NROWS 48000
#define KDIM 512
#define NE 320
#define GE 640
#define DDIM 384
#define ODIM 768
#define CB_OFF 36864000ul
#define SC_OFF 67584000ul
#define MARGIN 4e-3f

// hi/lo f16 scratch lives in the quantized region of d_out (fully rewritten later)
#define XHI_B 0ul
#define XLO_B 49152000ul
#define WHI_B 98304000ul
#define WLO_B 98959360ul

using f16x8 = __attribute__((ext_vector_type(8))) _Float16;
using f32x4 = __attribute__((ext_vector_type(4))) float;

#define GLD16(gp, lp)                                                          \
    __builtin_amdgcn_global_load_lds(                                          \
        (const __attribute__((address_space(1))) uint32_t*)(gp),               \
        (__attribute__((address_space(3))) uint32_t*)(lp), 16, 0, 0)

// ---------------- split f32 -> f16 hi + f16 lo -----------------------------
__global__ __launch_bounds__(256) void split16(const float* __restrict__ src,
                                               _Float16* __restrict__ hi,
                                               _Float16* __restrict__ lo,
                                               int n8)
{
    int i = blockIdx.x * 256 + threadIdx.x;
    if (i >= n8) return;
    float4 v0 = *((const float4*)src + 2 * (size_t)i);
    float4 v1 = *((const float4*)src + 2 * (size_t)i + 1);
    float x[8] = {v0.x, v0.y, v0.z, v0.w, v1.x, v1.y, v1.z, v1.w};
    f16x8 h, l;
    #pragma unroll
    for (int k = 0; k < 8; ++k) {
        _Float16 hh = (_Float16)x[k];
        h[k] = hh;
        l[k] = (_Float16)(x[k] - (float)hh);
    }
    *(f16x8*)(hi + (size_t)i * 8) = h;
    *(f16x8*)(lo + (size_t)i * 8) = l;
}

// ---------------- Kernel A: logits = X @ W^T + b via split-f16 MFMA --------
__global__ __launch_bounds__(256) void gemm_mfma(
    const _Float16* __restrict__ Xh, const _Float16* __restrict__ Xl,
    const _Float16* __restrict__ Wh, const _Float16* __restrict__ Wl,
    const float* __restrict__ bvec, float* __restrict__ Lout)
{
    __shared__ _Float16 lds[16384];             // 32 KB: Ah|Al|Bh|Bl, each [128][32]
    _Float16* Ah = lds;
    _Float16* Al = lds + 4096;
    _Float16* Bh = lds + 8192;
    _Float16* Bl = lds + 12288;

    // bijective XCD swizzle (nwg=1875, n-fastest so A-panels get L2 reuse)
    const int bid = blockIdx.x;
    const int q8 = 1875 / 8, r8 = 1875 % 8;
    const int xcd = bid & 7, wi = bid >> 3;
    const int wg = (xcd < r8 ? xcd * (q8 + 1) : r8 * (q8 + 1) + (xcd - r8) * q8) + wi;
    const int bm = wg / 5, bn = wg % 5;

    const int tid = threadIdx.x;
    const int wid = tid >> 6, lane = tid & 63;
    const int srow = lane >> 2;                  // staging: row-in-chunk
    const int sc8 = (lane & 3) * 8;              // staging: col (halves)
    const int fr = lane & 15, fq = lane >> 4;    // fragment lane decomposition
    const int wm = (wid >> 1) * 64, wn = (wid & 1) * 64;

    const _Float16* Ahg = Xh + (size_t)(bm * 128) * KDIM;
    const _Float16* Alg = Xl + (size_t)(bm * 128) * KDIM;
    const _Float16* Bhg = Wh + (size_t)(bn * 128) * KDIM;
    const _Float16* Blg = Wl + (size_t)(bn * 128) * KDIM;

    f32x4 acc[4][4];
    #pragma unroll
    for (int i = 0; i < 4; ++i)
        #pragma unroll
        for (int j = 0; j < 4; ++j)
            acc[i][j] = (f32x4){0.f, 0.f, 0.f, 0.f};

    for (int kk = 0; kk < 16; ++kk) {
        const int kh = kk * 32;
        #pragma unroll
        for (int q = 0; q < 2; ++q) {
            const int c = wid * 2 + q;           // chunk: 16 rows x 64B
            const size_t go = (size_t)(c * 16 + srow) * KDIM + kh + sc8;
            GLD16(Ahg + go, Ah + c * 512);
            GLD16(Alg + go, Al + c * 512);
            GLD16(Bhg + go, Bh + c * 512);
            GLD16(Blg + go, Bl + c * 512);
        }
        __syncthreads();

        f16x8 ah[4], al[4], bh[4], bl[4];
        #pragma unroll
        for (int i = 0; i < 4; ++i) {
            const int ro = (wm + i * 16 + fr) * 32 + fq * 8;
            ah[i] = *(const f16x8*)&Ah[ro];
            al[i] = *(const f16x8*)&Al[ro];
            const int co = (wn + i * 16 + fr) * 32 + fq * 8;
            bh[i] = *(const f16x8*)&Bh[co];
            bl[i] = *(const f16x8*)&Bl[co];
        }
        #pragma unroll
        for (int i = 0; i < 4; ++i)
            #pragma unroll
            for (int j = 0; j < 4; ++j) {
                acc[i][j] = __builtin_amdgcn_mfma_f32_16x16x32_f16(ah[i], bh[j], acc[i][j], 0, 0, 0);
                acc[i][j] = __builtin_amdgcn_mfma_f32_16x16x32_f16(ah[i], bl[j], acc[i][j], 0, 0, 0);
                acc[i][j] = __builtin_amdgcn_mfma_f32_16x16x32_f16(al[i], bh[j], acc[i][j], 0, 0, 0);
            }
        __syncthreads();
    }

    // C/D layout: col = lane&15, row = (lane>>4)*4 + reg   [m89-verified]
    #pragma unroll
    for (int i = 0; i < 4; ++i) {
        #pragma unroll
        for (int r = 0; r < 4; ++r) {
            const int m = bm * 128 + wm + i * 16 + fq * 4 + r;
            float* orow = Lout + (size_t)m * GE + bn * 128 + wn;
            #pragma unroll
            for (int j = 0; j < 4; ++j) {
                const int n = bn * 128 + wn + j * 16 + fr;
                orow[j * 16 + fr] = acc[i][j][r] + bvec[n];
            }
        }
    }
}

// ---------------- Kernel B: per-row epilogue ------------------------------
__device__ __forceinline__ bool better(float a, int ia, float b, int ib) {
    return (a > b) || (a == b && ia < ib);
}

__device__ __forceinline__ void top2_half(const float* v, int il,
                                          float& v1, int& i1, float& v2, int& i2)
{
    v1 = -3.4e38f; i1 = 0x7fffffff;
    v2 = -3.4e38f; i2 = 0x7fffffff;
    #pragma unroll
    for (int i = 0; i < 10; ++i) {
        int e = il + 32 * i;
        float x = v[i];
        if (better(x, e, v1, i1)) { v2 = v1; i2 = i1; v1 = x; i1 = e; }
        else if (better(x, e, v2, i2)) { v2 = x; i2 = e; }
    }
    #pragma unroll
    for (int m = 1; m <= 16; m <<= 1) {
        float ov1 = __shfl_xor(v1, m); int oi1 = __shfl_xor(i1, m);
        float ov2 = __shfl_xor(v2, m); int oi2 = __shfl_xor(i2, m);
        float lv; int li;
        if (better(ov1, oi1, v1, i1)) { lv = v1; li = i1; v1 = ov1; i1 = oi1; }
        else { lv = ov1; li = oi1; }
        if (better(lv, li, v2, i2)) { v2 = lv; i2 = li; }
        if (better(ov2, oi2, v2, i2)) { v2 = ov2; i2 = oi2; }
    }
}

// fp64 re-resolution of a near-tied argmax between candidates c1,c2
__device__ int resolve2(const float* __restrict__ X, const float* __restrict__ W,
                        const float* __restrict__ bvec, const float* __restrict__ Urow,
                        int n, int h, int c1, int c2, bool gum, int il)
{
    const float* xr = X + (size_t)n * KDIM;
    const float* w1 = W + (size_t)(h * NE + c1) * KDIM;
    const float* w2 = W + (size_t)(h * NE + c2) * KDIM;
    double d1 = 0.0, d2 = 0.0;
    #pragma unroll
    for (int j = 0; j < 16; ++j) {
        int k = il + 32 * j;
        double xv = (double)xr[k];
        d1 += xv * (double)w1[k];
        d2 += xv * (double)w2[k];
    }
    #pragma unroll
    for (int m = 1; m <= 16; m <<= 1) {
        d1 += __shfl_xor(d1, m);
        d2 += __shfl_xor(d2, m);
    }
    d1 += (double)bvec[h * NE + c1];
    d2 += (double)bvec[h * NE + c2];
    if (gum) {
        d1 += -log(-log((double)Urow[c1] + 1e-10) + 1e-10);
        d2 += -log(-log((double)Urow[c2] + 1e-10) + 1e-10);
    }
    return (d2 > d1 || (d2 == d1 && c2 < c1)) ? c2 : c1;
}

__global__ __launch_bounds__(256) void epilogue_kernel(
    const float* __restrict__ X, const float* __restrict__ W,
    const float* __restrict__ bvec, const float* __restrict__ entries,
    const float* __restrict__ gumbel, float* __restrict__ out,
    float* __restrict__ gavgp, unsigned int* __restrict__ gcnt)
{
    __shared__ float s_avgp[GE];
    __shared__ unsigned int s_cnt[GE];
    const int tid = threadIdx.x;
    for (int i = tid; i < GE; i += 256) { s_avgp[i] = 0.f; s_cnt[i] = 0u; }
    __syncthreads();

    const int wave = tid >> 6, lane = tid & 63;
    const int h = lane >> 5, il = lane & 31;

    float accp[10];
    #pragma unroll
    for (int i = 0; i < 10; ++i) accp[i] = 0.f;

    float* cb = out + CB_OFF;

    for (int rr = 0; rr < 8; ++rr) {
        const int n = blockIdx.x * 32 + wave * 8 + rr;
        float* Lrow = cb + (size_t)n * GE + h * NE;
        const float* Urow = gumbel + (size_t)(2 * n + h) * NE;

        float lg[10], zg[10];
        #pragma unroll
        for (int i = 0; i < 10; ++i) {
            int e = il + 32 * i;
            lg[i] = Lrow[e];
            float gn = -logf(-logf(Urow[e] + 1e-10f) + 1e-10f);
            zg[i] = lg[i] + gn;
        }

        float pv1, pv2; int pi1, pi2;
        top2_half(lg, il, pv1, pi1, pv2, pi2);
        float gv1, gv2; int gi1, gi2;
        top2_half(zg, il, gv1, gi1, gv2, gi2);

        int k_plain = pi1;
        if (pv1 - pv2 < MARGIN)
            k_plain = resolve2(X, W, bvec, Urow, n, h, pi1, pi2, false, il);
        int k_g = gi1;
        if (gv1 - gv2 < MARGIN)
            k_g = resolve2(X, W, bvec, Urow, n, h, gi1, gi2, true, il);

        float s = 0.f, ex[10];
        #pragma unroll
        for (int i = 0; i < 10; ++i) { ex[i] = expf(lg[i] - pv1); s += ex[i]; }
        #pragma unroll
        for (int m = 1; m <= 16; m <<= 1) s += __shfl_xor(s, m);
        float inv = 1.f / s;
        #pragma unroll
        for (int i = 0; i < 10; ++i) accp[i] += ex[i] * inv;

        if (il == 0) atomicAdd(&s_cnt[h * NE + k_plain], 1u);

        #pragma unroll
        for (int i = 0; i < 10; ++i) {
            int e = il + 32 * i;
            Lrow[e] = (e == k_g) ? 1.f : 0.f;
        }
        const float* ent = entries + (size_t)(h * NE + k_g) * DDIM;
        float* qrow = out + (size_t)n * ODIM + h * DDIM;
        #pragma unroll
        for (int j = 0; j < 12; ++j) {
            int d = il + 32 * j;
            qrow[d] = ent[d];
        }
    }

    #pragma unroll
    for (int i = 0; i < 10; ++i)
        atomicAdd(&s_avgp[h * NE + il + 32 * i], accp[i]);
    __syncthreads();
    for (int i = tid; i < GE; i += 256) {
        atomicAdd(&gavgp[i], s_avgp[i]);
        unsigned int c = s_cnt[i];
        if (c) atomicAdd(&gcnt[i], c);
    }
}

// ---------------- Kernel C: perplexity scalars ----------------------------
__global__ void finalize_kernel(const float* __restrict__ gavgp,
                                const unsigned int* __restrict__ gcnt,
                                float* __restrict__ out)
{
    __shared__ double sc[GE], sp[GE];
    const int t = threadIdx.x;
    if (t < GE) {
        double hp = (double)gcnt[t] * (1.0 / 48000.0);
        sc[t] = hp * log(hp + 1e-7);
        double ap = (double)gavgp[t] * (1.0 / 48000.0);
        sp[t] = ap * log(ap + 1e-7);
    }
    __syncthreads();
    if (t == 0) {
        double c0 = 0, c1 = 0, p0 = 0, p1 = 0;
        for (int e = 0; e < NE; ++e) { c0 += sc[e]; p0 += sp[e]; }
        for (int e = NE; e < GE; ++e) { c1 += sc[e]; p1 += sp[e]; }
        out[SC_OFF]     = (float)(exp(-c0) + exp(-c1));
        out[SC_OFF + 1] = (float)(exp(-p0) + exp(-p1));
    }
}

// ---------------- launch --------------------------------------------------
extern "C" void kernel_launch(void* const* d_in, const int* in_sizes, int n_in,
                              void* d_out, int out_size, void* d_ws, size_t ws_size,
                              hipStream_t stream)
{
    const float* X       = (const float*)d_in[0];
    const float* W       = (const float*)d_in[1];
    const float* bvec    = (const float*)d_in[2];
    const float* entries = (const float*)d_in[3];
    const float* gumbel  = (const float*)d_in[4];
    float* out = (float*)d_out;
    char* ob = (char*)d_out;

    _Float16* Xh = (_Float16*)(ob + XHI_B);
    _Float16* Xl = (_Float16*)(ob + XLO_B);
    _Float16* Wh = (_Float16*)(ob + WHI_B);
    _Float16* Wl = (_Float16*)(ob + WLO_B);

    float* gavgp = (float*)d_ws;
    unsigned int* gcnt = (unsigned int*)((char*)d_ws + GE * sizeof(float));

    hipMemsetAsync(d_ws, 0, GE * 8, stream);
    split16<<<12000, 256, 0, stream>>>(X, Xh, Xl, 3072000);   // 48000*512/8
    split16<<<160,   256, 0, stream>>>(W, Wh, Wl, 40960);     // 640*512/8
    gemm_mfma<<<1875, 256, 0, stream>>>(Xh, Xl, Wh, Wl, bvec, out + CB_OFF);
    epilogue_kernel<<<1500, 256, 0, stream>>>(X, W, bvec, entries, gumbel, out, gavgp, gcnt);
    finalize_kernel<<<1, 640, 0, stream>>>(gavgp, gcnt, out);
}